// Round 1
// baseline (2058.474 us; speedup 1.0000x reference)
//
#include <hip/hip_runtime.h>
#include <hip/hip_bf16.h>
#include <cstdint>
#include <cstddef>

typedef __bf16 bf16_t;
typedef __bf16 bf16x8 __attribute__((ext_vector_type(8)));
typedef float  f32x4  __attribute__((ext_vector_type(4)));

#define MFMA16(a, b, c) __builtin_amdgcn_mfma_f32_16x16x32_bf16((a), (b), (c), 0, 0, 0)

constexpr int D_MODEL = 1024;
constexpr int NHEAD   = 16;
constexpr int DHEAD   = 64;
constexpr int SEQ     = 2048;
constexpr int BATCH   = 4;
constexpr int BS      = BATCH * SEQ;   // 8192 rows (flattened B*S)
constexpr int BH      = BATCH * NHEAD; // 64 (b,h) pairs
constexpr float INV_TEMP = 0.125f;     // 1/sqrt(64)
constexpr int LDST = 48;               // LDS row stride in bf16 elems (32 data + 16 pad, 96 B rows)

// ---------------------------------------------------------------------------
// Reductions (wave = 64 lanes)
// ---------------------------------------------------------------------------
__device__ __forceinline__ float wave_max(float v) {
#pragma unroll
    for (int off = 32; off > 0; off >>= 1) v = fmaxf(v, __shfl_xor(v, off));
    return v;
}
__device__ __forceinline__ float wave_sum(float v) {
#pragma unroll
    for (int off = 32; off > 0; off >>= 1) v += __shfl_xor(v, off);
    return v;
}

// ---------------------------------------------------------------------------
// Kernel 1: QKV projections.  Y = X @ W.T  (M=8192, N=1024, K=1024), z picks q/k/v.
// Outputs: Qh [B,H,S,dh] bf16 (scaled 1/TEMP), Kh [B,H,S,dh] bf16, Vt [B,H,dh,S] bf16.
// ---------------------------------------------------------------------------
__global__ __launch_bounds__(256) void proj_qkv(
    const float* __restrict__ q, const float* __restrict__ k, const float* __restrict__ v,
    const float* __restrict__ wq, const float* __restrict__ wk, const float* __restrict__ wv,
    bf16_t* __restrict__ Qh, bf16_t* __restrict__ Kh, bf16_t* __restrict__ Vt)
{
    __shared__ bf16_t As[64 * LDST];
    __shared__ bf16_t Bs[64 * LDST];
    const int z  = blockIdx.z;
    const float* __restrict__ X = (z == 0) ? q : (z == 1) ? k : v;
    const float* __restrict__ W = (z == 0) ? wq : (z == 1) ? wk : wv;
    const int m0 = blockIdx.y * 64;
    const int n0 = blockIdx.x * 64;
    const int tid  = threadIdx.x;
    const int lane = tid & 63, wid = tid >> 6;
    const int quad = lane >> 4, l16 = lane & 15;
    const int srow = tid >> 2, scol = (tid & 3) * 8;

    f32x4 acc[4] = {};
    for (int k0 = 0; k0 < D_MODEL; k0 += 32) {
        const float* ap = X + (size_t)(m0 + srow) * D_MODEL + k0 + scol;
        const float* bp = W + (size_t)(n0 + srow) * D_MODEL + k0 + scol;
        float4 a0 = *(const float4*)ap, a1 = *(const float4*)(ap + 4);
        float4 b0 = *(const float4*)bp, b1 = *(const float4*)(bp + 4);
        bf16x8 av, bv;
        av[0] = (bf16_t)a0.x; av[1] = (bf16_t)a0.y; av[2] = (bf16_t)a0.z; av[3] = (bf16_t)a0.w;
        av[4] = (bf16_t)a1.x; av[5] = (bf16_t)a1.y; av[6] = (bf16_t)a1.z; av[7] = (bf16_t)a1.w;
        bv[0] = (bf16_t)b0.x; bv[1] = (bf16_t)b0.y; bv[2] = (bf16_t)b0.z; bv[3] = (bf16_t)b0.w;
        bv[4] = (bf16_t)b1.x; bv[5] = (bf16_t)b1.y; bv[6] = (bf16_t)b1.z; bv[7] = (bf16_t)b1.w;
        *(bf16x8*)&As[srow * LDST + scol] = av;
        *(bf16x8*)&Bs[srow * LDST + scol] = bv;
        __syncthreads();
        bf16x8 af = *(const bf16x8*)&As[(wid * 16 + l16) * LDST + quad * 8];
#pragma unroll
        for (int t = 0; t < 4; ++t) {
            bf16x8 bf = *(const bf16x8*)&Bs[(t * 16 + l16) * LDST + quad * 8];
            acc[t] = MFMA16(af, bf, acc[t]);
        }
        __syncthreads();
    }
#pragma unroll
    for (int t = 0; t < 4; ++t) {
#pragma unroll
        for (int r = 0; r < 4; ++r) {
            const int gm = m0 + wid * 16 + quad * 4 + r;
            const int gn = n0 + t * 16 + l16;
            const float val = acc[t][r];
            const int b = gm >> 11, s = gm & (SEQ - 1);
            const int h = gn >> 6,  d = gn & (DHEAD - 1);
            if (z == 0)
                Qh[(((size_t)(b * NHEAD + h)) * SEQ + s) * DHEAD + d] = (bf16_t)(val * INV_TEMP);
            else if (z == 1)
                Kh[(((size_t)(b * NHEAD + h)) * SEQ + s) * DHEAD + d] = (bf16_t)val;
            else
                Vt[(((size_t)(b * NHEAD + h)) * DHEAD + d) * SEQ + s] = (bf16_t)val;
        }
    }
}

// ---------------------------------------------------------------------------
// Kernel 2: raw scores = Qh_scaled @ Kh^T per (b,h).  M=N=2048, K=64.
// ---------------------------------------------------------------------------
__global__ __launch_bounds__(256) void qk_scores(
    const bf16_t* __restrict__ Qh, const bf16_t* __restrict__ Kh, float* __restrict__ attn)
{
    __shared__ bf16_t As[64 * LDST];
    __shared__ bf16_t Bs[64 * LDST];
    const int z  = blockIdx.z;
    const int m0 = blockIdx.y * 64;
    const int n0 = blockIdx.x * 64;
    const int tid  = threadIdx.x;
    const int lane = tid & 63, wid = tid >> 6;
    const int quad = lane >> 4, l16 = lane & 15;
    const int srow = tid >> 2, scol = (tid & 3) * 8;

    f32x4 acc[4] = {};
    for (int k0 = 0; k0 < DHEAD; k0 += 32) {
        *(bf16x8*)&As[srow * LDST + scol] =
            *(const bf16x8*)(Qh + ((size_t)z * SEQ + m0 + srow) * DHEAD + k0 + scol);
        *(bf16x8*)&Bs[srow * LDST + scol] =
            *(const bf16x8*)(Kh + ((size_t)z * SEQ + n0 + srow) * DHEAD + k0 + scol);
        __syncthreads();
        bf16x8 af = *(const bf16x8*)&As[(wid * 16 + l16) * LDST + quad * 8];
#pragma unroll
        for (int t = 0; t < 4; ++t) {
            bf16x8 bf = *(const bf16x8*)&Bs[(t * 16 + l16) * LDST + quad * 8];
            acc[t] = MFMA16(af, bf, acc[t]);
        }
        __syncthreads();
    }
#pragma unroll
    for (int t = 0; t < 4; ++t) {
#pragma unroll
        for (int r = 0; r < 4; ++r) {
            const int gm = m0 + wid * 16 + quad * 4 + r;
            const int gn = n0 + t * 16 + l16;
            attn[((size_t)z * SEQ + gm) * SEQ + gn] = acc[t][r];
        }
    }
}

// ---------------------------------------------------------------------------
// Kernel 3: in-place row softmax over 2048 keys. One block (256 thr) per row.
// ---------------------------------------------------------------------------
__global__ __launch_bounds__(256) void softmax_rows(float* __restrict__ attn)
{
    __shared__ float redm[4];
    __shared__ float reds[4];
    const size_t row = blockIdx.x;
    float* p = attn + row * (size_t)SEQ;
    const int tid = threadIdx.x;
    float4 x0 = ((const float4*)p)[tid];
    float4 x1 = ((const float4*)p)[tid + 256];

    float m = fmaxf(fmaxf(fmaxf(x0.x, x0.y), fmaxf(x0.z, x0.w)),
                    fmaxf(fmaxf(x1.x, x1.y), fmaxf(x1.z, x1.w)));
    m = wave_max(m);
    if ((tid & 63) == 0) redm[tid >> 6] = m;
    __syncthreads();
    m = fmaxf(fmaxf(redm[0], redm[1]), fmaxf(redm[2], redm[3]));

    x0.x = __expf(x0.x - m); x0.y = __expf(x0.y - m);
    x0.z = __expf(x0.z - m); x0.w = __expf(x0.w - m);
    x1.x = __expf(x1.x - m); x1.y = __expf(x1.y - m);
    x1.z = __expf(x1.z - m); x1.w = __expf(x1.w - m);

    float s = x0.x + x0.y + x0.z + x0.w + x1.x + x1.y + x1.z + x1.w;
    s = wave_sum(s);
    if ((tid & 63) == 0) reds[tid >> 6] = s;
    __syncthreads();
    s = reds[0] + reds[1] + reds[2] + reds[3];
    const float inv = 1.0f / s;

    x0.x *= inv; x0.y *= inv; x0.z *= inv; x0.w *= inv;
    x1.x *= inv; x1.y *= inv; x1.z *= inv; x1.w *= inv;
    ((float4*)p)[tid]       = x0;
    ((float4*)p)[tid + 256] = x1;
}

// ---------------------------------------------------------------------------
// Kernel 4: O = attn @ V per (b,h).  M=2048, N=64, K=2048. attn fp32 -> bf16 at staging.
// Output Oh: [B,S,D] merged-head bf16.
// ---------------------------------------------------------------------------
__global__ __launch_bounds__(256) void attn_v(
    const float* __restrict__ attn, const bf16_t* __restrict__ Vt, bf16_t* __restrict__ Oh)
{
    __shared__ bf16_t As[64 * LDST];
    __shared__ bf16_t Bs[64 * LDST];
    const int z  = blockIdx.z;
    const int m0 = blockIdx.y * 64;
    const int tid  = threadIdx.x;
    const int lane = tid & 63, wid = tid >> 6;
    const int quad = lane >> 4, l16 = lane & 15;
    const int srow = tid >> 2, scol = (tid & 3) * 8;

    f32x4 acc[4] = {};
    for (int k0 = 0; k0 < SEQ; k0 += 32) {
        const float* ap = attn + ((size_t)z * SEQ + m0 + srow) * SEQ + k0 + scol;
        float4 a0 = *(const float4*)ap, a1 = *(const float4*)(ap + 4);
        bf16x8 av;
        av[0] = (bf16_t)a0.x; av[1] = (bf16_t)a0.y; av[2] = (bf16_t)a0.z; av[3] = (bf16_t)a0.w;
        av[4] = (bf16_t)a1.x; av[5] = (bf16_t)a1.y; av[6] = (bf16_t)a1.z; av[7] = (bf16_t)a1.w;
        *(bf16x8*)&As[srow * LDST + scol] = av;
        *(bf16x8*)&Bs[srow * LDST + scol] =
            *(const bf16x8*)(Vt + ((size_t)z * DHEAD + srow) * SEQ + k0 + scol);
        __syncthreads();
        bf16x8 af = *(const bf16x8*)&As[(wid * 16 + l16) * LDST + quad * 8];
#pragma unroll
        for (int t = 0; t < 4; ++t) {
            bf16x8 bf = *(const bf16x8*)&Bs[(t * 16 + l16) * LDST + quad * 8];
            acc[t] = MFMA16(af, bf, acc[t]);
        }
        __syncthreads();
    }
    const int b = z >> 4, h = z & 15;
#pragma unroll
    for (int t = 0; t < 4; ++t) {
#pragma unroll
        for (int r = 0; r < 4; ++r) {
            const int gm = m0 + wid * 16 + quad * 4 + r;   // s index
            const int gn = t * 16 + l16;                   // d index (0..63)
            Oh[((size_t)(b * SEQ) + gm) * D_MODEL + h * DHEAD + gn] = (bf16_t)acc[t][r];
        }
    }
}

// ---------------------------------------------------------------------------
// Kernel 5: out = Oh @ w_fc.T + residual(q).  M=8192, N=1024, K=1024. fp32 out (pre-LN).
// ---------------------------------------------------------------------------
__global__ __launch_bounds__(256) void out_proj(
    const bf16_t* __restrict__ Oh, const float* __restrict__ wfc,
    const float* __restrict__ q, float* __restrict__ out)
{
    __shared__ bf16_t As[64 * LDST];
    __shared__ bf16_t Bs[64 * LDST];
    const int m0 = blockIdx.y * 64;
    const int n0 = blockIdx.x * 64;
    const int tid  = threadIdx.x;
    const int lane = tid & 63, wid = tid >> 6;
    const int quad = lane >> 4, l16 = lane & 15;
    const int srow = tid >> 2, scol = (tid & 3) * 8;

    f32x4 acc[4] = {};
    for (int k0 = 0; k0 < D_MODEL; k0 += 32) {
        *(bf16x8*)&As[srow * LDST + scol] =
            *(const bf16x8*)(Oh + (size_t)(m0 + srow) * D_MODEL + k0 + scol);
        const float* bp = wfc + (size_t)(n0 + srow) * D_MODEL + k0 + scol;
        float4 b0 = *(const float4*)bp, b1 = *(const float4*)(bp + 4);
        bf16x8 bv;
        bv[0] = (bf16_t)b0.x; bv[1] = (bf16_t)b0.y; bv[2] = (bf16_t)b0.z; bv[3] = (bf16_t)b0.w;
        bv[4] = (bf16_t)b1.x; bv[5] = (bf16_t)b1.y; bv[6] = (bf16_t)b1.z; bv[7] = (bf16_t)b1.w;
        *(bf16x8*)&Bs[srow * LDST + scol] = bv;
        __syncthreads();
        bf16x8 af = *(const bf16x8*)&As[(wid * 16 + l16) * LDST + quad * 8];
#pragma unroll
        for (int t = 0; t < 4; ++t) {
            bf16x8 bf = *(const bf16x8*)&Bs[(t * 16 + l16) * LDST + quad * 8];
            acc[t] = MFMA16(af, bf, acc[t]);
        }
        __syncthreads();
    }
#pragma unroll
    for (int t = 0; t < 4; ++t) {
#pragma unroll
        for (int r = 0; r < 4; ++r) {
            const int gm = m0 + wid * 16 + quad * 4 + r;
            const int gn = n0 + t * 16 + l16;
            out[(size_t)gm * D_MODEL + gn] = acc[t][r] + q[(size_t)gm * D_MODEL + gn];
        }
    }
}

// ---------------------------------------------------------------------------
// Kernel 6: in-place LayerNorm per row of 1024, eps=1e-6, affine.
// ---------------------------------------------------------------------------
__global__ __launch_bounds__(256) void layernorm_rows(
    float* __restrict__ out, const float* __restrict__ lw, const float* __restrict__ lb)
{
    __shared__ float rs_[4];
    __shared__ float rss_[4];
    const size_t row = blockIdx.x;
    float* p = out + row * (size_t)D_MODEL;
    const int tid = threadIdx.x;
    float4 x = ((const float4*)p)[tid];
    float s  = x.x + x.y + x.z + x.w;
    float ss = x.x * x.x + x.y * x.y + x.z * x.z + x.w * x.w;
    s  = wave_sum(s);
    ss = wave_sum(ss);
    if ((tid & 63) == 0) { rs_[tid >> 6] = s; rss_[tid >> 6] = ss; }
    __syncthreads();
    s  = rs_[0] + rs_[1] + rs_[2] + rs_[3];
    ss = rss_[0] + rss_[1] + rss_[2] + rss_[3];
    const float mean = s * (1.0f / D_MODEL);
    const float var  = ss * (1.0f / D_MODEL) - mean * mean;
    const float rstd = rsqrtf(var + 1e-6f);
    float4 w = ((const float4*)lw)[tid];
    float4 b = ((const float4*)lb)[tid];
    float4 y;
    y.x = (x.x - mean) * rstd * w.x + b.x;
    y.y = (x.y - mean) * rstd * w.y + b.y;
    y.z = (x.z - mean) * rstd * w.z + b.z;
    y.w = (x.w - mean) * rstd * w.w + b.w;
    ((float4*)p)[tid] = y;
}

// ---------------------------------------------------------------------------
extern "C" void kernel_launch(void* const* d_in, const int* in_sizes, int n_in,
                              void* d_out, int out_size, void* d_ws, size_t ws_size,
                              hipStream_t stream)
{
    (void)in_sizes; (void)n_in; (void)out_size; (void)ws_size;
    const float* q   = (const float*)d_in[0];
    const float* k   = (const float*)d_in[1];
    const float* v   = (const float*)d_in[2];
    const float* wq  = (const float*)d_in[3];
    const float* wk  = (const float*)d_in[4];
    const float* wv  = (const float*)d_in[5];
    const float* wfc = (const float*)d_in[6];
    const float* lw  = (const float*)d_in[7];
    const float* lb  = (const float*)d_in[8];

    float* out  = (float*)d_out;
    float* attn = out + (size_t)BS * D_MODEL;   // 8,388,608 floats in, then 268,435,456

    const size_t HSZ = (size_t)BH * SEQ * DHEAD;  // 8,388,608 bf16 elems (16 MB)
    bf16_t* Qh = (bf16_t*)d_ws;
    bf16_t* Kh = Qh + HSZ;
    bf16_t* Vt = Kh + HSZ;
    bf16_t* Oh = Vt + HSZ;                        // [BS, D_MODEL] bf16

    hipLaunchKernelGGL(proj_qkv, dim3(D_MODEL / 64, BS / 64, 3), dim3(256), 0, stream,
                       q, k, v, wq, wk, wv, Qh, Kh, Vt);
    hipLaunchKernelGGL(qk_scores, dim3(SEQ / 64, SEQ / 64, BH), dim3(256), 0, stream,
                       Qh, Kh, attn);
    hipLaunchKernelGGL(softmax_rows, dim3(BH * SEQ), dim3(256), 0, stream, attn);
    hipLaunchKernelGGL(attn_v, dim3(1, SEQ / 64, BH), dim3(256), 0, stream, attn, Vt, Oh);
    hipLaunchKernelGGL(out_proj, dim3(D_MODEL / 64, BS / 64, 1), dim3(256), 0, stream,
                       Oh, wfc, q, out);
    hipLaunchKernelGGL(layernorm_rows, dim3(BS), dim3(256), 0, stream, out, lw, lb);
}